// Round 1
// baseline (266.703 us; speedup 1.0000x reference)
//
#include <hip/hip_runtime.h>

#define T_LEN 256
#define B_TOT 8192
#define RSCALE 3.2734375f
#define L2E    1.44269504f
#define LN2    0.693147180559945f

typedef __attribute__((ext_vector_type(2))) _Float16 h2;

__device__ __forceinline__ h2 pkrtz(float lo, float hi) {
    return __builtin_bit_cast(h2, __builtin_amdgcn_cvt_pkrtz(lo, hi));
}
__device__ __forceinline__ float ror8f(float x) {
    int xi = __float_as_int(x);
    int r = __builtin_amdgcn_update_dpp(xi, xi, 0x128, 0xF, 0xF, false); // ROW_ROR:8
    return __int_as_float(r);
}
__device__ __forceinline__ h2 ror1h(h2 x) {
    int xi = __builtin_bit_cast(int, x);
    int r = __builtin_amdgcn_update_dpp(xi, xi, 0x121, 0xF, 0xF, false); // ROW_ROR:1
    return __builtin_bit_cast(h2, r);
}

// ---------------- fully fused: ctrl pack + recurrence + gold, one kernel ----------------
// Block = 256 threads = 16 sequences (16 lanes each). Prologue computes the ctrl
// bytes + trans/start gold parts for this block's 16 seqs into LDS (coalesced:
// iteration m covers one full contiguous sequence), then the proven dot2-f16
// recurrence runs unchanged with cq sourced from LDS broadcast reads.
__global__ __launch_bounds__(256, 2) void crf_fused(
    const float* __restrict__ em, const float* __restrict__ trans,
    const float* __restrict__ start, const float* __restrict__ cw,
    const int* __restrict__ tags, const int* __restrict__ w2w,
    const int* __restrict__ ic,   const int* __restrict__ ds,
    float* __restrict__ out)
{
    __shared__ float tl[1024];
    __shared__ float cw_l[16];
    __shared__ float st_l[16];
    __shared__ uint4 ctrl4[256];    // 16 seqs x 256 ctrl bytes (4 KB)
    __shared__ float gl[4096];      // 16 seqs x 256 gold partials (16 KB)

    const int tid = threadIdx.x;
    for (int i = tid; i < 1024; i += 256) tl[i] = trans[i];
    if (tid < 16)      cw_l[tid]      = cw[tid];
    else if (tid < 32) st_l[tid - 16] = start[tid - 16];
    __syncthreads();

    // ---- prologue: ctrl byte (tag | tidx<<4) + trans/start gold part -> LDS ----
    {
        unsigned char* ctrl_lds = (unsigned char*)ctrl4;
        const int s0 = blockIdx.x * 16;
        const int t  = tid;
#pragma unroll 4
        for (int m = 0; m < 16; ++m) {
            int idx = (s0 + m) * 256 + t;
            int tag = tags[idx];
            unsigned byte = (unsigned)tag;
            float g;
            if (t == 0) {
                g = cw_l[tag] * st_l[tag];
            } else {
                int off  = (s0 + m) * 255 + (t - 1);
                int tidx = (w2w[off] == 1) ? 0 : ((ic[off] == 0) ? 1 : ((ds[off] == 0) ? 2 : 3));
                byte |= (unsigned)(tidx << 4);
                int ptag = tags[idx - 1];
                g = cw_l[tag] * tl[tidx * 256 + ptag * 16 + tag];
            }
            ctrl_lds[m * 256 + t] = (unsigned char)byte;
            gl[m * 256 + t] = g;
        }
    }
    __syncthreads();

    const int j   = tid & 15;
    const int grp = tid >> 4;
    const int seq = blockIdx.x * 16 + grp;

    // DPP rotation-direction probe (proven in R1/R2)
    int pr    = __builtin_amdgcn_update_dpp(j, j, 0x121, 0xF, 0xF, false);
    int delta = (pr - j) & 15;

    // half2 diagonal tables: D[c][r] = ( E_c[(j+r*d)&15][j] , E_c[(j+(r+8)*d)&15][j] )
    h2 D[4][8];
#pragma unroll
    for (int c = 0; c < 4; ++c)
#pragma unroll
        for (int r = 0; r < 8; ++r) {
            float lo = __expf(tl[c * 256 + ((j + r * delta) & 15) * 16 + j]);
            float hi = __expf(tl[c * 256 + ((j + (r + 8) * delta) & 15) * 16 + j]);
            D[c][r] = pkrtz(lo, hi);
        }

    const float cw_j = cw_l[j];
    const float st_j = st_l[j];
    const float* ep  = em + (size_t)seq * 4096 + j;
    const uint4* cp  = ctrl4 + grp * 16;   // 16 uint4 per seq, LDS broadcast

    // 16-deep emission ring (1 f32/lane/step)
    float emr[16];
#pragma unroll
    for (int k = 0; k < 16; ++k) emr[k] = ep[k * 16];
    uint4 cq = cp[0], cqn = cp[1];

    float u, ge, logC = 5.545177444479562f;   // 8*ln2: u0 pre-scaled 2^-8
    {
        int tag0 = (int)(cq.x & 15u);
        u  = __expf(st_j + emr[0]) * 0.00390625f;
        ge = (j == tag0) ? cw_j * emr[0] : 0.0f;
        emr[0] = ep[16 * 16];                  // refill slot 0 with t=16
    }

    auto STEP = [&](int t, int k, bool pf) __attribute__((always_inline)) {
        unsigned dw = (k < 4) ? cq.x : (k < 8) ? cq.y : (k < 12) ? cq.z : cq.w;
        int sh = 8 * (k & 3);
        int tag   = (int)((dw >> sh) & 15u);
        bool modd = ((dw >> (sh + 4)) & 1u) != 0u;   // tidx odd
        bool mhi  = ((dw >> (sh + 5)) & 1u) != 0u;   // tidx >= 2

        // pair (u_j, u_{j+8d}) in f16; rotate pair with ror1; 8 dot2s
        float uh = ror8f(u);
        h2 P = pkrtz(u, uh);
        float s = 0.0f;
#pragma unroll
        for (int r = 0; r < 8; ++r) {
            if (r) P = ror1h(P);
            h2 e01 = modd ? D[1][r] : D[0][r];
            h2 e23 = modd ? D[3][r] : D[2][r];
            h2 e   = mhi ? e23 : e01;
            s = __builtin_amdgcn_fdot2(P, e, s, false);
        }
        float exf = __builtin_exp2f(fmaf(emr[k], L2E, -RSCALE * L2E));
        if (j == tag) ge = fmaf(cw_j, emr[k], ge);   // gold em-term
        u = s * exf;
        if (pf) emr[k] = ep[(size_t)(t + 16) * 16];  // refill 16 steps ahead
        if ((k & 7) == 7) {                          // exact pow2 renorm, -4 bias
            float mx = u;
            mx = fmaxf(mx, __shfl_xor(mx, 1, 64));
            mx = fmaxf(mx, __shfl_xor(mx, 2, 64));
            mx = fmaxf(mx, __shfl_xor(mx, 4, 64));
            mx = fmaxf(mx, __shfl_xor(mx, 8, 64));
            int e2; (void)frexpf(mx, &e2);
            u = ldexpf(u, -e2 - 4);
            logC += (float)(e2 + 4) * LN2;
        }
    };

    // block 0: t=1..15
#pragma unroll
    for (int k = 1; k < 16; ++k) STEP(k, k, true);
    // blocks 1..14 with prefetch
    for (int blk = 1; blk < 15; ++blk) {
        cq = cqn;
        cqn = cp[blk + 1];
#pragma unroll
        for (int k = 0; k < 16; ++k) STEP(blk * 16 + k, k, true);
    }
    // peeled last block: t=240..255, no prefetch
    cq = cqn;
#pragma unroll
    for (int k = 0; k < 16; ++k) STEP(240 + k, k, false);

    // gold trans/start partial for this seq, from LDS (written in prologue)
    float gp = 0.0f;
#pragma unroll
    for (int q = 0; q < 16; ++q) gp += gl[grp * 256 + j + 16 * q];

    // group reductions
    float su = u, gs = ge + gp;
#pragma unroll
    for (int m = 1; m < 16; m <<= 1) {
        su += __shfl_xor(su, m, 64);
        gs += __shfl_xor(gs, m, 64);
    }
    if (j == 0) {
        out[seq]         = gs;
        out[B_TOT + seq] = logf(su) + 255.0f * RSCALE + logC;
    }
}

extern "C" void kernel_launch(void* const* d_in, const int* in_sizes, int n_in,
                              void* d_out, int out_size, void* d_ws, size_t ws_size,
                              hipStream_t stream) {
    const float* emissions     = (const float*)d_in[0];
    const int*   tags          = (const int*)  d_in[1];
    const int*   who2who       = (const int*)  d_in[2];
    const int*   init_count    = (const int*)  d_in[3];
    const int*   distance      = (const int*)  d_in[4];
    const float* class_weights = (const float*)d_in[5];
    const float* trans_stack   = (const float*)d_in[6];
    const float* start_scores  = (const float*)d_in[7];
    float* out = (float*)d_out;
    (void)d_ws; (void)ws_size;

    hipLaunchKernelGGL(crf_fused, dim3(B_TOT / 16), dim3(256), 0, stream,
                       emissions, trans_stack, start_scores, class_weights,
                       tags, who2who, init_count, distance, out);
}